// Round 14
// baseline (6117.933 us; speedup 1.0000x reference)
//
#include <hip/hip_runtime.h>
#include <hip/hip_bf16.h>

#define LEN   4096
#define EMB   300
#define HALF  256
#define G4    1024   // 4*HALF
#define HID   512
#define OUT_N 20

#if defined(__has_builtin)
#  if __has_builtin(__builtin_amdgcn_sdot4)
#    define HAVE_SDOT4 1
#  endif
#  if __has_builtin(__builtin_amdgcn_rcpf)
#    define RCPF(x) __builtin_amdgcn_rcpf(x)
#  endif
#endif
#ifndef RCPF
#  define RCPF(x) (1.0f/(x))
#endif

__device__ __forceinline__ int dot4(int a, int b, int c){
#ifdef HAVE_SDOT4
  return __builtin_amdgcn_sdot4(a, b, c, false);
#else
  c += (int)(signed char)(a)     * (int)(signed char)(b);
  c += (int)(signed char)(a>>8)  * (int)(signed char)(b>>8);
  c += (int)(signed char)(a>>16) * (int)(signed char)(b>>16);
  c += (int)(a>>24)              * (int)(b>>24);
  return c;
#endif
}

__device__ __forceinline__ float sigm_(float x){ return RCPF(1.f + __expf(-x)); }
__device__ __forceinline__ float tanh_(float x){ return 2.f*RCPF(1.f + __expf(-2.f*x)) - 1.f; }
__device__ __forceinline__ float bf2f(unsigned short u){ return __uint_as_float(((unsigned)u)<<16); }

// ---------------- prep: quantize Whh rows to i8 + bias sums -----------------
__global__ void prep_quant(const float* __restrict__ WhhF, const float* __restrict__ WhhB,
    const float* __restrict__ bihF, const float* __restrict__ bhhF,
    const float* __restrict__ bihB, const float* __restrict__ bhhB,
    signed char* __restrict__ Wq, float* __restrict__ wsc, float* __restrict__ bsum)
{
  int r = blockIdx.x*256 + threadIdx.x;
  if (r >= 2*G4) return;
  int dir = r >> 10, row = r & 1023;
  const float4* Wr = (const float4*)((dir ? WhhB : WhhF) + (size_t)row*HALF);
  float m = 0.f;
  #pragma unroll 4
  for (int k=0;k<HALF/4;k++){
    float4 v = Wr[k];
    m = fmaxf(m, fmaxf(fmaxf(fabsf(v.x),fabsf(v.y)), fmaxf(fabsf(v.z),fabsf(v.w))));
  }
  float inv = 127.f / fmaxf(m, 1e-30f);
  int* q = (int*)(Wq + (size_t)r*HALF);
  #pragma unroll 4
  for (int k=0;k<HALF/4;k++){
    float4 v = Wr[k];
    int b0 = __float2int_rn(v.x*inv); b0 = b0>127?127:(b0<-127?-127:b0);
    int b1 = __float2int_rn(v.y*inv); b1 = b1>127?127:(b1<-127?-127:b1);
    int b2 = __float2int_rn(v.z*inv); b2 = b2>127?127:(b2<-127?-127:b2);
    int b3 = __float2int_rn(v.w*inv); b3 = b3>127?127:(b3<-127?-127:b3);
    q[k] = (b0&255) | ((b1&255)<<8) | ((b2&255)<<16) | ((b3&255)<<24);
  }
  wsc[r]  = (m/127.f)*(1.f/127.f);        // scale for (i32 dot) -> f32
  bsum[r] = dir ? (bihB[row]+bhhB[row]) : (bihF[row]+bhhF[row]);
}

// ---------------- Wv_ae = AE @ W_v_a^T + b_v_a  [20,512] --------------------
__global__ void wv_kernel(const float* __restrict__ AE, const float* __restrict__ Wv,
                          const float* __restrict__ bv, float* __restrict__ WvAE)
{
  __shared__ float ae[EMB];
  const int o = blockIdx.x, tid = threadIdx.x;
  for (int k=tid;k<EMB;k+=256) ae[k] = AE[(size_t)o*EMB+k];
  __syncthreads();
  for (int j=tid;j<HID;j+=256){
    const float* wr = Wv + (size_t)j*EMB;
    float d = 0.f;
    for (int k=0;k<EMB;k++) d += ae[k]*wr[k];
    WvAE[(size_t)o*HID + j] = d + bv[j];
  }
}

// ---- generic C[M,N] = A[idx(m),:K] * B[n,:K]^T + bias[n]; out f32 or bf16 ---
// gperm: permute output column g*256+j -> j*4+g (gate-interleaved pre layout)
__global__ __launch_bounds__(256) void gemm_tn(
    const float* __restrict__ A, int lda, const int* __restrict__ idx,
    const float* __restrict__ B, int ldb, const float* __restrict__ bias,
    float* __restrict__ Cf, __hip_bfloat16* __restrict__ Cb, int ldc,
    int M, int N, int K, int gperm)
{
  __shared__ __align__(16) float As[16][68];
  __shared__ __align__(16) float Bs[16][68];
  const int tid = threadIdx.x;
  const int bm = blockIdx.x<<6, bn = blockIdx.y<<6;
  const int lm = tid>>2;            // 0..63 row loaded by this thread
  const int lk = (tid&3)<<2;        // 0,4,8,12 k offset
  const int ty = tid>>4, tx = tid&15;
  int arow = bm + lm;
  if (idx) arow = idx[arow];
  const float* Ap = A + (size_t)arow*lda + lk;
  const float* Bp = B + (size_t)(bn+lm)*ldb + lk;
  float acc[4][4];
  #pragma unroll
  for (int i=0;i<4;i++)
    #pragma unroll
    for (int j=0;j<4;j++) acc[i][j]=0.f;

  for (int k0=0;k0<K;k0+=16){
    float4 av, bv;
    if (k0+16 <= K){
      av = *(const float4*)(Ap+k0);
      bv = *(const float4*)(Bp+k0);
    } else {
      float a0[4], b0[4];
      #pragma unroll
      for (int j=0;j<4;j++){
        int kk = k0+lk+j;
        a0[j] = (kk<K)? Ap[k0+j] : 0.f;
        b0[j] = (kk<K)? Bp[k0+j] : 0.f;
      }
      av = make_float4(a0[0],a0[1],a0[2],a0[3]);
      bv = make_float4(b0[0],b0[1],b0[2],b0[3]);
    }
    __syncthreads();
    As[lk+0][lm]=av.x; As[lk+1][lm]=av.y; As[lk+2][lm]=av.z; As[lk+3][lm]=av.w;
    Bs[lk+0][lm]=bv.x; Bs[lk+1][lm]=bv.y; Bs[lk+2][lm]=bv.z; Bs[lk+3][lm]=bv.w;
    __syncthreads();
    #pragma unroll
    for (int kk=0;kk<16;kk++){
      const float4 a = *(const float4*)(&As[kk][ty<<2]);
      const float4 b = *(const float4*)(&Bs[kk][tx<<2]);
      acc[0][0]+=a.x*b.x; acc[0][1]+=a.x*b.y; acc[0][2]+=a.x*b.z; acc[0][3]+=a.x*b.w;
      acc[1][0]+=a.y*b.x; acc[1][1]+=a.y*b.y; acc[1][2]+=a.y*b.z; acc[1][3]+=a.y*b.w;
      acc[2][0]+=a.z*b.x; acc[2][1]+=a.z*b.y; acc[2][2]+=a.z*b.z; acc[2][3]+=a.z*b.w;
      acc[3][0]+=a.w*b.x; acc[3][1]+=a.w*b.y; acc[3][2]+=a.w*b.z; acc[3][3]+=a.w*b.w;
    }
  }
  const int cm = bm+(ty<<2), cn = bn+(tx<<2);
  #pragma unroll
  for (int i=0;i<4;i++){
    #pragma unroll
    for (int j=0;j<4;j++){
      float v = acc[i][j] + (bias ? bias[cn+j] : 0.f);
      int col = cn+j;
      int pc = gperm ? (((col&255)<<2) | (col>>8)) : col;
      if (Cb) Cb[(size_t)(cm+i)*ldc + pc] = __float2bfloat16(v);
      else    Cf[(size_t)(cm+i)*ldc + pc] = v;
    }
  }
}

// -------------------- persistent bidirectional LSTM scan --------------------
// NEW config: 2 blocks x 256 threads (4 waves = 1 wave/SIMD) with
// waves_per_eu(1,1) -> 512-unified-reg/wave budget. Thread = unit j, owning
// ALL 4 gate rows x full K=256 (256 weight ints, demand ~300 << 512): the
// allocator's arch/accum split has room to keep everything in arch VGPRs.
// No cross-lane at all: i,f,g~,o, c, h are thread-local. h broadcast-read
// from double-buffered LDS; ONE barrier/step. LDS pad keeps the occupancy
// estimate at 1 block/CU consistent with (1,1).
__global__ __attribute__((amdgpu_flat_work_group_size(256,256), amdgpu_waves_per_eu(1,1)))
void lstm_scan(
    const __hip_bfloat16* __restrict__ preF,   // [LEN][1024] gate-permuted [s][4j+g]
    const __hip_bfloat16* __restrict__ preB,
    const signed char* __restrict__ Wq,        // [2][1024][256] rows g*256+j
    const float* __restrict__ wsc,             // [2][1024]
    float* __restrict__ hs, float* __restrict__ ht)
{
  const int dir = blockIdx.x;
  const int tid = threadIdx.x;   // 0..255 = unit j
  __shared__ int hq[2][64];      // double-buffered 256 x i8 h
  __shared__ int pad_[24320];    // ~95KB occupancy limiter: 1 block/CU
  ((volatile int*)pad_)[tid] = 0;

  const signed char* wp = Wq + (size_t)dir*G4*HALF;
  const int4* pg0 = (const int4*)(wp + (size_t)(0*HALF + tid)*HALF);
  const int4* pg1 = (const int4*)(wp + (size_t)(1*HALF + tid)*HALF);
  const int4* pg2 = (const int4*)(wp + (size_t)(2*HALF + tid)*HALF);
  const int4* pg3 = (const int4*)(wp + (size_t)(3*HALF + tid)*HALF);

#define DECLW(g) int4 w##g##_0,w##g##_1,w##g##_2,w##g##_3,w##g##_4,w##g##_5,w##g##_6,w##g##_7, \
                      w##g##_8,w##g##_9,w##g##_10,w##g##_11,w##g##_12,w##g##_13,w##g##_14,w##g##_15;
  DECLW(0) DECLW(1) DECLW(2) DECLW(3)
#undef DECLW
#define LOADW(g, pg) \
  w##g##_0=pg[0]; w##g##_1=pg[1]; w##g##_2=pg[2]; w##g##_3=pg[3]; \
  w##g##_4=pg[4]; w##g##_5=pg[5]; w##g##_6=pg[6]; w##g##_7=pg[7]; \
  w##g##_8=pg[8]; w##g##_9=pg[9]; w##g##_10=pg[10]; w##g##_11=pg[11]; \
  w##g##_12=pg[12]; w##g##_13=pg[13]; w##g##_14=pg[14]; w##g##_15=pg[15];
  LOADW(0, pg0) LOADW(1, pg1) LOADW(2, pg2) LOADW(3, pg3)
#undef LOADW
#define PIN(v) asm volatile("" : "+v"(v.x),"+v"(v.y),"+v"(v.z),"+v"(v.w))
#define PINW(g) PIN(w##g##_0);PIN(w##g##_1);PIN(w##g##_2);PIN(w##g##_3); \
                PIN(w##g##_4);PIN(w##g##_5);PIN(w##g##_6);PIN(w##g##_7); \
                PIN(w##g##_8);PIN(w##g##_9);PIN(w##g##_10);PIN(w##g##_11); \
                PIN(w##g##_12);PIN(w##g##_13);PIN(w##g##_14);PIN(w##g##_15);
  PINW(0) PINW(1) PINW(2) PINW(3)
#undef PINW
#undef PIN

  const float sc0 = wsc[dir*G4 + 0*HALF + tid];
  const float sc1 = wsc[dir*G4 + 1*HALF + tid];
  const float sc2 = wsc[dir*G4 + 2*HALF + tid];
  const float sc3 = wsc[dir*G4 + 3*HALF + tid];

  const int t0 = dir ? (LEN-1) : 0;
  const int pstep = dir ? -G4 : G4;            // row stride in ushorts
  const unsigned short* pp = (const unsigned short*)(dir ? preB : preF)
                             + (size_t)t0*G4 + tid*4;
  float* hsp = hs + (size_t)t0*HID + dir*HALF + tid;
  const int hstep = dir ? -HID : HID;

  if (tid < 64) hq[0][tid] = 0;
  float c = 0.f;
  ushort4 pv = *(const ushort4*)pp;
  __syncthreads();

  for (int s=0;s<LEN;s++){
    ushort4 pnext = pv;
    if (s < LEN-1){ pp += pstep; pnext = *(const ushort4*)pp; }
    const int4* hb = (const int4*)(&hq[s&1][0]);   // broadcast reads
    int a0=0,a1=0,a2=0,a3=0;     // even-chunk chains (per gate)
    int b0=0,b1=0,b2=0,b3=0;     // odd-chunk chains
#define CHUNK(cc, x0,x1,x2,x3) { int4 hv = hb[cc]; \
    x0=dot4(w0_##cc.x,hv.x,x0); x0=dot4(w0_##cc.y,hv.y,x0); x0=dot4(w0_##cc.z,hv.z,x0); x0=dot4(w0_##cc.w,hv.w,x0); \
    x1=dot4(w1_##cc.x,hv.x,x1); x1=dot4(w1_##cc.y,hv.y,x1); x1=dot4(w1_##cc.z,hv.z,x1); x1=dot4(w1_##cc.w,hv.w,x1); \
    x2=dot4(w2_##cc.x,hv.x,x2); x2=dot4(w2_##cc.y,hv.y,x2); x2=dot4(w2_##cc.z,hv.z,x2); x2=dot4(w2_##cc.w,hv.w,x2); \
    x3=dot4(w3_##cc.x,hv.x,x3); x3=dot4(w3_##cc.y,hv.y,x3); x3=dot4(w3_##cc.z,hv.z,x3); x3=dot4(w3_##cc.w,hv.w,x3); }
    CHUNK(0,  a0,a1,a2,a3)
    CHUNK(1,  b0,b1,b2,b3)
    CHUNK(2,  a0,a1,a2,a3)
    CHUNK(3,  b0,b1,b2,b3)
    CHUNK(4,  a0,a1,a2,a3)
    CHUNK(5,  b0,b1,b2,b3)
    CHUNK(6,  a0,a1,a2,a3)
    CHUNK(7,  b0,b1,b2,b3)
    CHUNK(8,  a0,a1,a2,a3)
    CHUNK(9,  b0,b1,b2,b3)
    CHUNK(10, a0,a1,a2,a3)
    CHUNK(11, b0,b1,b2,b3)
    CHUNK(12, a0,a1,a2,a3)
    CHUNK(13, b0,b1,b2,b3)
    CHUNK(14, a0,a1,a2,a3)
    CHUNK(15, b0,b1,b2,b3)
#undef CHUNK
    a0 += b0; a1 += b1; a2 += b2; a3 += b3;
    // ---- all 4 gates thread-local: no cross-lane at all ----
    float g0 = bf2f(pv.x) + (float)a0*sc0;   // i
    float g1 = bf2f(pv.y) + (float)a1*sc1;   // f
    float g2 = bf2f(pv.z) + (float)a2*sc2;   // g~
    float g3 = bf2f(pv.w) + (float)a3*sc3;   // o
    float ig = sigm_(g0), fg = sigm_(g1), gg = tanh_(g2), og = sigm_(g3);
    c = fmaf(fg, c, ig*gg);
    float h = og * tanh_(c);
    *hsp = h;
    ((signed char*)&hq[(s+1)&1][0])[tid] = (signed char)__float2int_rn(h * 127.f);
    if (s == LEN-1) ht[dir*HALF + tid] = h;
    hsp += hstep;
    pv = pnext;
    __syncthreads();
  }
}

// ---------------- xw = ht @ W_x_a^T + b_x_a [512] ---------------------------
__global__ __launch_bounds__(512) void xw_kernel(const float* __restrict__ ht,
    const float* __restrict__ Wx, const float* __restrict__ bx, float* __restrict__ xw)
{
  __shared__ float h[HID];
  const int tid = threadIdx.x;
  h[tid] = ht[tid];
  __syncthreads();
  const float* wr = Wx + (size_t)tid*HID;
  float d = 0.f;
  for (int k=0;k<HID;k++) d += h[k]*wr[k];
  xw[tid] = d + bx[tid];
}

// ------- scores[o,l] = w_a . tanh(Wh_out[l] + Wv_ae[o]) + b_w_a -------------
__global__ __launch_bounds__(256) void scores_kernel(
    const float* __restrict__ WhOut, const float* __restrict__ WvAE,
    const float* __restrict__ wa, const float* __restrict__ bwa,
    float* __restrict__ scores)
{
  __shared__ float red[4];
  const int l = blockIdx.x, tid = threadIdx.x;
  const int lane = tid & 63, wv = tid >> 6;
  const float wl0 = WhOut[(size_t)l*HID + tid];
  const float wl1 = WhOut[(size_t)l*HID + 256 + tid];
  const float wa0 = wa[tid], wa1 = wa[256+tid];
  const float bb = bwa[0];
  for (int o=0;o<OUT_N;o++){
    float v = wa0*tanh_(wl0 + WvAE[o*HID+tid]) + wa1*tanh_(wl1 + WvAE[o*HID+256+tid]);
    #pragma unroll
    for (int m=32;m;m>>=1) v += __shfl_xor(v, m, 64);
    if (lane==0) red[wv] = v;
    __syncthreads();
    if (tid==0) scores[(size_t)o*LEN + l] = red[0]+red[1]+red[2]+red[3] + bb;
    __syncthreads();
  }
}

// ------- softmax over l (per o) + r[o] = weights @ output2 ------------------
__global__ __launch_bounds__(512) void softmax_wsum(
    const float* __restrict__ scores, const float* __restrict__ hs, float* __restrict__ ratt)
{
  __shared__ float sm[LEN];
  __shared__ float red[8];
  __shared__ float bc[2];
  const int o = blockIdx.x, tid = threadIdx.x;
  const int lane = tid & 63, wv = tid >> 6;
  for (int l=tid;l<LEN;l+=512) sm[l] = scores[(size_t)o*LEN + l];
  __syncthreads();
  float mx = -1e30f;
  for (int l=tid;l<LEN;l+=512) mx = fmaxf(mx, sm[l]);
  #pragma unroll
  for (int m=32;m;m>>=1) mx = fmaxf(mx, __shfl_xor(mx, m, 64));
  if (lane==0) red[wv] = mx;
  __syncthreads();
  if (tid==0){ float m0=red[0]; for (int i=1;i<8;i++) m0=fmaxf(m0,red[i]); bc[0]=m0; }
  __syncthreads();
  const float m0 = bc[0];
  float s = 0.f;
  for (int l=tid;l<LEN;l+=512){ float e = __expf(sm[l]-m0); sm[l]=e; s+=e; }
  #pragma unroll
  for (int m=32;m;m>>=1) s += __shfl_xor(s, m, 64);
  if (lane==0) red[wv] = s;
  __syncthreads();
  if (tid==0){ float z=0.f; for (int i=0;i<8;i++) z+=red[i]; bc[1] = 1.f/z; }
  __syncthreads();
  const float rz = bc[1];
  float acc = 0.f;
  const float* hp = hs + tid;
  for (int l=0;l<LEN;l++) acc += sm[l]*hp[(size_t)l*HID];
  ratt[(size_t)o*HID + tid] = acc*rz;
}

// ------- out[o] = sigmoid( dec_W[o] . tanh(r W_p^T + b_p + xw) + dec_b ) ----
__global__ __launch_bounds__(256) void final_kernel(
    const float* __restrict__ ratt, const float* __restrict__ Wp, const float* __restrict__ bp,
    const float* __restrict__ xw, const float* __restrict__ decW, const float* __restrict__ decb,
    float* __restrict__ outp)
{
  __shared__ float rv[HID];
  __shared__ float rr[HID];
  __shared__ float red[4];
  const int o = blockIdx.x, tid = threadIdx.x;
  const int lane = tid & 63, wv = tid >> 6;
  rv[tid]     = ratt[(size_t)o*HID + tid];
  rv[256+tid] = ratt[(size_t)o*HID + 256 + tid];
  __syncthreads();
  #pragma unroll
  for (int jj=0;jj<2;jj++){
    int j = tid + jj*256;
    const float* wr = Wp + (size_t)j*HID;
    float d = 0.f;
    for (int k=0;k<HID;k++) d += rv[k]*wr[k];
    rr[j] = tanh_(d + bp[j] + xw[j]);
  }
  __syncthreads();
  float v = rr[tid]*decW[(size_t)o*HID+tid] + rr[256+tid]*decW[(size_t)o*HID+256+tid];
  #pragma unroll
  for (int m=32;m;m>>=1) v += __shfl_xor(v, m, 64);
  if (lane==0) red[wv] = v;
  __syncthreads();
  if (tid==0) outp[o] = sigm_(red[0]+red[1]+red[2]+red[3] + decb[o]);
}

// ---------------------------------------------------------------------------
extern "C" void kernel_launch(void* const* d_in, const int* in_sizes, int n_in,
                              void* d_out, int out_size, void* d_ws, size_t ws_size,
                              hipStream_t stream)
{
  (void)in_sizes; (void)n_in; (void)out_size; (void)ws_size;
  const int*   sent  = (const int*)  d_in[0];
  const float* embed = (const float*)d_in[1];
  const float* WihF  = (const float*)d_in[2];
  const float* WhhF  = (const float*)d_in[3];
  const float* bihF  = (const float*)d_in[4];
  const float* bhhF  = (const float*)d_in[5];
  const float* WihB  = (const float*)d_in[6];
  const float* WhhB  = (const float*)d_in[7];
  const float* bihB  = (const float*)d_in[8];
  const float* bhhB  = (const float*)d_in[9];
  const float* AE    = (const float*)d_in[10];
  const float* W_h   = (const float*)d_in[11];
  const float* b_h   = (const float*)d_in[12];
  const float* W_v   = (const float*)d_in[13];
  const float* b_v   = (const float*)d_in[14];
  const float* w_a   = (const float*)d_in[15];
  const float* b_w   = (const float*)d_in[16];
  const float* W_p   = (const float*)d_in[17];
  const float* b_p   = (const float*)d_in[18];
  const float* W_x   = (const float*)d_in[19];
  const float* b_x   = (const float*)d_in[20];
  const float* decW  = (const float*)d_in[21];
  const float* decb  = (const float*)d_in[22];
  float* outp = (float*)d_out;

  char* ws = (char*)d_ws;
  size_t off = 0;
  auto alloc = [&](size_t n){ size_t p = off; off += (n + 255) & ~(size_t)255; return p; };
  __hip_bfloat16* preF  = (__hip_bfloat16*)(ws + alloc((size_t)LEN*G4*2));
  __hip_bfloat16* preB  = (__hip_bfloat16*)(ws + alloc((size_t)LEN*G4*2));
  float*          hsbuf = (float*)        (ws + alloc((size_t)LEN*HID*4));
  float*          WhOut = (float*)        (ws + alloc((size_t)LEN*HID*4));
  signed char*    Wq    = (signed char*)  (ws + alloc((size_t)2*G4*HALF));
  float*          wsc   = (float*)        (ws + alloc((size_t)2*G4*4));
  float*          bsum  = (float*)        (ws + alloc((size_t)2*G4*4));
  float*          htv   = (float*)        (ws + alloc((size_t)HID*4));
  float*          WvAE  = (float*)        (ws + alloc((size_t)OUT_N*HID*4));
  float*          xw    = (float*)        (ws + alloc((size_t)HID*4));
  float*          scor  = (float*)        (ws + alloc((size_t)OUT_N*LEN*4));
  float*          ratt  = (float*)        (ws + alloc((size_t)OUT_N*HID*4));

  // prep
  prep_quant<<<8, 256, 0, stream>>>(WhhF, WhhB, bihF, bhhF, bihB, bhhB, Wq, wsc, bsum);
  wv_kernel<<<OUT_N, 256, 0, stream>>>(AE, W_v, b_v, WvAE);

  // pre = gather(embed, sent) @ Wih^T + (bih+bhh), bf16, gate-permuted cols
  gemm_tn<<<dim3(LEN/64, G4/64), 256, 0, stream>>>(
      embed, EMB, sent, WihF, EMB, bsum,        nullptr, preF, G4, LEN, G4, EMB, 1);
  gemm_tn<<<dim3(LEN/64, G4/64), 256, 0, stream>>>(
      embed, EMB, sent, WihB, EMB, bsum + G4,   nullptr, preB, G4, LEN, G4, EMB, 1);

  // sequential bidirectional scan (2 persistent blocks, 256 threads each)
  lstm_scan<<<2, 256, 0, stream>>>(preF, preB, Wq, wsc, hsbuf, htv);

  // Wh_out = output2 @ W_h_a^T + b_h_a
  gemm_tn<<<dim3(LEN/64, HID/64), 256, 0, stream>>>(
      hsbuf, HID, nullptr, W_h, HID, b_h, WhOut, nullptr, HID, LEN, HID, HID, 0);

  xw_kernel<<<1, 512, 0, stream>>>(htv, W_x, b_x, xw);
  scores_kernel<<<LEN, 256, 0, stream>>>(WhOut, WvAE, w_a, b_w, scor);
  softmax_wsum<<<OUT_N, 512, 0, stream>>>(scor, hsbuf, ratt);
  final_kernel<<<OUT_N, 256, 0, stream>>>(ratt, W_p, b_p, xw, decW, decb, outp);
}

// Round 15
// 4716.822 us; speedup vs baseline: 1.2970x; 1.2970x over previous
//
#include <hip/hip_runtime.h>
#include <hip/hip_bf16.h>

#define LEN   4096
#define EMB   300
#define HALF  256
#define G4    1024   // 4*HALF
#define HID   512
#define OUT_N 20

#if defined(__has_builtin)
#  if __has_builtin(__builtin_amdgcn_rcpf)
#    define RCPF(x) __builtin_amdgcn_rcpf(x)
#  endif
#endif
#ifndef RCPF
#  define RCPF(x) (1.0f/(x))
#endif

typedef int v4i __attribute__((ext_vector_type(4)));
__device__ __forceinline__ v4i tov(int4 a){ v4i r; r[0]=a.x; r[1]=a.y; r[2]=a.z; r[3]=a.w; return r; }
__device__ __forceinline__ int4 fromv(v4i a){ return make_int4(a[0],a[1],a[2],a[3]); }

__device__ __forceinline__ float sigm_(float x){ return RCPF(1.f + __expf(-x)); }
__device__ __forceinline__ float tanh_(float x){ return 2.f*RCPF(1.f + __expf(-2.f*x)) - 1.f; }
__device__ __forceinline__ float bf2f(unsigned short u){ return __uint_as_float(((unsigned)u)<<16); }

__device__ __forceinline__ int qpack4(const float* p, float inv){
  int b0 = __float2int_rn(p[0]*inv); b0 = b0>127?127:(b0<-127?-127:b0);
  int b1 = __float2int_rn(p[1]*inv); b1 = b1>127?127:(b1<-127?-127:b1);
  int b2 = __float2int_rn(p[2]*inv); b2 = b2>127?127:(b2<-127?-127:b2);
  int b3 = __float2int_rn(p[3]*inv); b3 = b3>127?127:(b3<-127?-127:b3);
  return (b0&255) | ((b1&255)<<8) | ((b2&255)<<16) | ((b3&255)<<24);
}

// ---- prep: quantize Whh rows to i8, scatter into MFMA A-fragment layout ----
// Fragment layout (16x16x64 i8 MFMA, per direction): row_global = 4*unit+gate
// (gate-interleaved). wave w = rg>>7, tile m = (rg>>4)&7, A-row = rg&15.
// Lane l of wave w holds A[16m+(l&15)][64t + (l>>4)*16 + e*4 + b] in dword
// (m*4+t)*4+e of its 128-dword block. Thread-block-contiguous storage:
// Wq2[(dir*512 + w*64 + lane)*128 + idx] dwords.
__global__ void prep_quant(const float* __restrict__ WhhF, const float* __restrict__ WhhB,
    const float* __restrict__ bihF, const float* __restrict__ bhhF,
    const float* __restrict__ bihB, const float* __restrict__ bhhB,
    signed char* __restrict__ Wq2, float* __restrict__ wsc4, float* __restrict__ bsum)
{
  int r = blockIdx.x*256 + threadIdx.x;
  if (r >= 2*G4) return;
  int dir = r >> 10, rr = r & 1023;
  int gate = rr >> 8, unit = rr & 255;
  const float* Wr = (dir ? WhhB : WhhF) + (size_t)rr*HALF;
  float m = 0.f;
  #pragma unroll 4
  for (int k=0;k<HALF;k+=4){
    m = fmaxf(m, fmaxf(fmaxf(fabsf(Wr[k]),fabsf(Wr[k+1])), fmaxf(fabsf(Wr[k+2]),fabsf(Wr[k+3]))));
  }
  float inv = 127.f / fmaxf(m, 1e-30f);

  int rg   = 4*unit + gate;
  int wv_  = rg >> 7;
  int mt   = (rg >> 4) & 7;
  int lrow = rg & 15;
  signed char* base = Wq2 + ((size_t)(dir*512 + wv_*64 + lrow))*512;
  #pragma unroll
  for (int t=0;t<4;t++){
    #pragma unroll
    for (int hi=0;hi<4;hi++){
      int* dst = (int*)(base + (size_t)hi*16*512 + (mt*4 + t)*16);
      #pragma unroll
      for (int e=0;e<4;e++){
        int kb = 64*t + 16*hi + 4*e;
        dst[e] = qpack4(Wr + kb, inv);
      }
    }
  }
  wsc4[(dir*256 + unit)*4 + gate] = (m/127.f)*(1.f/127.f);
  bsum[r] = dir ? (bihB[rr]+bhhB[rr]) : (bihF[rr]+bhhF[rr]);
}

// ---------------- Wv_ae = AE @ W_v_a^T + b_v_a  [20,512] --------------------
__global__ void wv_kernel(const float* __restrict__ AE, const float* __restrict__ Wv,
                          const float* __restrict__ bv, float* __restrict__ WvAE)
{
  __shared__ float ae[EMB];
  const int o = blockIdx.x, tid = threadIdx.x;
  for (int k=tid;k<EMB;k+=256) ae[k] = AE[(size_t)o*EMB+k];
  __syncthreads();
  for (int j=tid;j<HID;j+=256){
    const float* wr = Wv + (size_t)j*EMB;
    float d = 0.f;
    for (int k=0;k<EMB;k++) d += ae[k]*wr[k];
    WvAE[(size_t)o*HID + j] = d + bv[j];
  }
}

// ---- generic C[M,N] = A[idx(m),:K] * B[n,:K]^T + bias[n]; out f32 or bf16 ---
// gperm: permute output column g*256+j -> j*4+g (gate-interleaved pre layout)
__global__ __launch_bounds__(256) void gemm_tn(
    const float* __restrict__ A, int lda, const int* __restrict__ idx,
    const float* __restrict__ B, int ldb, const float* __restrict__ bias,
    float* __restrict__ Cf, __hip_bfloat16* __restrict__ Cb, int ldc,
    int M, int N, int K, int gperm)
{
  __shared__ __align__(16) float As[16][68];
  __shared__ __align__(16) float Bs[16][68];
  const int tid = threadIdx.x;
  const int bm = blockIdx.x<<6, bn = blockIdx.y<<6;
  const int lm = tid>>2;            // 0..63 row loaded by this thread
  const int lk = (tid&3)<<2;        // 0,4,8,12 k offset
  const int ty = tid>>4, tx = tid&15;
  int arow = bm + lm;
  if (idx) arow = idx[arow];
  const float* Ap = A + (size_t)arow*lda + lk;
  const float* Bp = B + (size_t)(bn+lm)*ldb + lk;
  float acc[4][4];
  #pragma unroll
  for (int i=0;i<4;i++)
    #pragma unroll
    for (int j=0;j<4;j++) acc[i][j]=0.f;

  for (int k0=0;k0<K;k0+=16){
    float4 av, bv;
    if (k0+16 <= K){
      av = *(const float4*)(Ap+k0);
      bv = *(const float4*)(Bp+k0);
    } else {
      float a0[4], b0[4];
      #pragma unroll
      for (int j=0;j<4;j++){
        int kk = k0+lk+j;
        a0[j] = (kk<K)? Ap[k0+j] : 0.f;
        b0[j] = (kk<K)? Bp[k0+j] : 0.f;
      }
      av = make_float4(a0[0],a0[1],a0[2],a0[3]);
      bv = make_float4(b0[0],b0[1],b0[2],b0[3]);
    }
    __syncthreads();
    As[lk+0][lm]=av.x; As[lk+1][lm]=av.y; As[lk+2][lm]=av.z; As[lk+3][lm]=av.w;
    Bs[lk+0][lm]=bv.x; Bs[lk+1][lm]=bv.y; Bs[lk+2][lm]=bv.z; Bs[lk+3][lm]=bv.w;
    __syncthreads();
    #pragma unroll
    for (int kk=0;kk<16;kk++){
      const float4 a = *(const float4*)(&As[kk][ty<<2]);
      const float4 b = *(const float4*)(&Bs[kk][tx<<2]);
      acc[0][0]+=a.x*b.x; acc[0][1]+=a.x*b.y; acc[0][2]+=a.x*b.z; acc[0][3]+=a.x*b.w;
      acc[1][0]+=a.y*b.x; acc[1][1]+=a.y*b.y; acc[1][2]+=a.y*b.z; acc[1][3]+=a.y*b.w;
      acc[2][0]+=a.z*b.x; acc[2][1]+=a.z*b.y; acc[2][2]+=a.z*b.z; acc[2][3]+=a.z*b.w;
      acc[3][0]+=a.w*b.x; acc[3][1]+=a.w*b.y; acc[3][2]+=a.w*b.z; acc[3][3]+=a.w*b.w;
    }
  }
  const int cm = bm+(ty<<2), cn = bn+(tx<<2);
  #pragma unroll
  for (int i=0;i<4;i++){
    #pragma unroll
    for (int j=0;j<4;j++){
      float v = acc[i][j] + (bias ? bias[cn+j] : 0.f);
      int col = cn+j;
      int pc = gperm ? (((col&255)<<2) | (col>>8)) : col;
      if (Cb) Cb[(size_t)(cm+i)*ldc + pc] = __float2bfloat16(v);
      else    Cf[(size_t)(cm+i)*ldc + pc] = v;
    }
  }
}

// -------------------- persistent bidirectional LSTM scan (MFMA) -------------
// 2 blocks x 512 threads (8 waves, 2/SIMD). Wave w owns fragment-rows
// [128w,128w+128) of the gate-interleaved 1024x256 Whh: 32 A-fragments = 128
// dwords/lane, consumed DIRECTLY from AGPRs by v_mfma_i32_16x16x64_i8 (zero
// restore cost — the escape from 5 rounds of accvgpr_read traffic).
// B = h broadcast to all 16 cols (4 conflict-free ds_read_b128), so every
// column of D is W·h. D (verified layout): lane l, reg g = row 4u+g of unit
// u = 32w+4m+(l>>4). Col-0 lanes ds_write_b128 gates to a 4KB buffer ->
// barrier -> threads 0..255 run the thread-local LSTM tail (same math as R14,
// absmax expected 0.001953125). Two barriers/step.
__global__ __attribute__((amdgpu_flat_work_group_size(512,512), amdgpu_waves_per_eu(2,2)))
void lstm_scan(
    const __hip_bfloat16* __restrict__ preF,   // [LEN][1024] gate-permuted [s][4u+g]
    const __hip_bfloat16* __restrict__ preB,
    const signed char* __restrict__ Wq2,       // fragment-packed, 512B/thread
    const float* __restrict__ wsc4,            // [2][256][4] unit-major scales
    float* __restrict__ hs, float* __restrict__ ht)
{
  const int dir = blockIdx.x;
  const int tid = threadIdx.x;   // 0..511
  const int l   = tid & 63;
  const int w   = tid >> 6;
  __shared__ __align__(16) int hq[2][64];      // double-buffered 256 x i8 h
  __shared__ __align__(16) int4 gbuf[256];     // per-unit i32 gates

  // ---- 32 A-fragments (128 dwords) ----
  const int4* wptr = (const int4*)(Wq2 + ((size_t)(dir*512 + tid))*512);
  int4 w00=wptr[0],  w01=wptr[1],  w02=wptr[2],  w03=wptr[3];
  int4 w10=wptr[4],  w11=wptr[5],  w12=wptr[6],  w13=wptr[7];
  int4 w20=wptr[8],  w21=wptr[9],  w22=wptr[10], w23=wptr[11];
  int4 w30=wptr[12], w31=wptr[13], w32=wptr[14], w33=wptr[15];
  int4 w40=wptr[16], w41=wptr[17], w42=wptr[18], w43=wptr[19];
  int4 w50=wptr[20], w51=wptr[21], w52=wptr[22], w53=wptr[23];
  int4 w60=wptr[24], w61=wptr[25], w62=wptr[26], w63=wptr[27];
  int4 w70=wptr[28], w71=wptr[29], w72=wptr[30], w73=wptr[31];

  // ---- tail state (threads 0..255 = unit u) ----
  const bool isTail = (tid < 256);
  const int u = tid;
  const int t0 = dir ? (LEN-1) : 0;
  const int pstep = dir ? -G4 : G4;            // row stride in ushorts
  const unsigned short* pp = (const unsigned short*)(dir ? preB : preF)
                             + (size_t)t0*G4 + u*4;
  float* hsp = hs + (size_t)t0*HID + dir*HALF + u;
  const int hstep = dir ? -HID : HID;
  float4 scv = make_float4(0.f,0.f,0.f,0.f);
  ushort4 pv = make_ushort4(0,0,0,0);
  float c = 0.f;
  if (isTail){
    scv = ((const float4*)wsc4)[dir*256 + u];
    pv  = *(const ushort4*)pp;
  }

  if (tid < 64) hq[0][tid] = 0;
  __syncthreads();

  const int bbase = (l >> 4) * 16;   // B-fragment byte offset within h buffer

  for (int s=0;s<LEN;s++){
    // prefetch next pre (hidden under MFMAs)
    ushort4 pnext = pv;
    if (isTail && s < LEN-1){ pp += pstep; pnext = *(const ushort4*)pp; }
    // ---- B fragments: h broadcast to all 16 columns ----
    const char* hb = (const char*)&hq[s&1][0];
    v4i B0 = tov(*(const int4*)(hb + bbase));
    v4i B1 = tov(*(const int4*)(hb +  64 + bbase));
    v4i B2 = tov(*(const int4*)(hb + 128 + bbase));
    v4i B3 = tov(*(const int4*)(hb + 192 + bbase));
    // ---- 32 MFMAs: 8 independent chains x 4 k-tiles ----
    v4i a0={0,0,0,0},a1={0,0,0,0},a2={0,0,0,0},a3={0,0,0,0};
    v4i a4={0,0,0,0},a5={0,0,0,0},a6={0,0,0,0},a7={0,0,0,0};
#define MF(acc, W, B) acc = __builtin_amdgcn_mfma_i32_16x16x64_i8(tov(W), B, acc, 0, 0, 0);
    MF(a0,w00,B0) MF(a1,w10,B0) MF(a2,w20,B0) MF(a3,w30,B0)
    MF(a4,w40,B0) MF(a5,w50,B0) MF(a6,w60,B0) MF(a7,w70,B0)
    MF(a0,w01,B1) MF(a1,w11,B1) MF(a2,w21,B1) MF(a3,w31,B1)
    MF(a4,w41,B1) MF(a5,w51,B1) MF(a6,w61,B1) MF(a7,w71,B1)
    MF(a0,w02,B2) MF(a1,w12,B2) MF(a2,w22,B2) MF(a3,w32,B2)
    MF(a4,w42,B2) MF(a5,w52,B2) MF(a6,w62,B2) MF(a7,w72,B2)
    MF(a0,w03,B3) MF(a1,w13,B3) MF(a2,w23,B3) MF(a3,w33,B3)
    MF(a4,w43,B3) MF(a5,w53,B3) MF(a6,w63,B3) MF(a7,w73,B3)
#undef MF
    // ---- col-0 lanes publish gates: unit 32w+4m+(l>>4) ----
    if ((l & 15) == 0){
      const int q = l >> 4;
      gbuf[32*w + 4*0 + q] = fromv(a0);
      gbuf[32*w + 4*1 + q] = fromv(a1);
      gbuf[32*w + 4*2 + q] = fromv(a2);
      gbuf[32*w + 4*3 + q] = fromv(a3);
      gbuf[32*w + 4*4 + q] = fromv(a4);
      gbuf[32*w + 4*5 + q] = fromv(a5);
      gbuf[32*w + 4*6 + q] = fromv(a6);
      gbuf[32*w + 4*7 + q] = fromv(a7);
    }
    __syncthreads();
    // ---- thread-local LSTM tail (threads 0..255, unit u) ----
    if (isTail){
      int4 gi = gbuf[u];
      float g0 = bf2f(pv.x) + (float)gi.x * scv.x;   // i
      float g1 = bf2f(pv.y) + (float)gi.y * scv.y;   // f
      float g2 = bf2f(pv.z) + (float)gi.z * scv.z;   // g~
      float g3 = bf2f(pv.w) + (float)gi.w * scv.w;   // o
      float ig = sigm_(g0), fg = sigm_(g1), gg = tanh_(g2), og = sigm_(g3);
      c = fmaf(fg, c, ig*gg);
      float h = og * tanh_(c);
      *hsp = h;
      ((signed char*)&hq[(s+1)&1][0])[u] = (signed char)__float2int_rn(h * 127.f);
      if (s == LEN-1) ht[dir*HALF + u] = h;
      hsp += hstep;
      pv = pnext;
    }
    __syncthreads();
  }
}

// ---------------- xw = ht @ W_x_a^T + b_x_a [512] ---------------------------
__global__ __launch_bounds__(512) void xw_kernel(const float* __restrict__ ht,
    const float* __restrict__ Wx, const float* __restrict__ bx, float* __restrict__ xw)
{
  __shared__ float h[HID];
  const int tid = threadIdx.x;
  h[tid] = ht[tid];
  __syncthreads();
  const float* wr = Wx + (size_t)tid*HID;
  float d = 0.f;
  for (int k=0;k<HID;k++) d += h[k]*wr[k];
  xw[tid] = d + bx[tid];
}

// ------- scores[o,l] = w_a . tanh(Wh_out[l] + Wv_ae[o]) + b_w_a -------------
__global__ __launch_bounds__(256) void scores_kernel(
    const float* __restrict__ WhOut, const float* __restrict__ WvAE,
    const float* __restrict__ wa, const float* __restrict__ bwa,
    float* __restrict__ scores)
{
  __shared__ float red[4];
  const int l = blockIdx.x, tid = threadIdx.x;
  const int lane = tid & 63, wv = tid >> 6;
  const float wl0 = WhOut[(size_t)l*HID + tid];
  const float wl1 = WhOut[(size_t)l*HID + 256 + tid];
  const float wa0 = wa[tid], wa1 = wa[256+tid];
  const float bb = bwa[0];
  for (int o=0;o<OUT_N;o++){
    float v = wa0*tanh_(wl0 + WvAE[o*HID+tid]) + wa1*tanh_(wl1 + WvAE[o*HID+256+tid]);
    #pragma unroll
    for (int m=32;m;m>>=1) v += __shfl_xor(v, m, 64);
    if (lane==0) red[wv] = v;
    __syncthreads();
    if (tid==0) scores[(size_t)o*LEN + l] = red[0]+red[1]+red[2]+red[3] + bb;
    __syncthreads();
  }
}

// ------- softmax over l (per o) + r[o] = weights @ output2 ------------------
__global__ __launch_bounds__(512) void softmax_wsum(
    const float* __restrict__ scores, const float* __restrict__ hs, float* __restrict__ ratt)
{
  __shared__ float sm[LEN];
  __shared__ float red[8];
  __shared__ float bc[2];
  const int o = blockIdx.x, tid = threadIdx.x;
  const int lane = tid & 63, wv = tid >> 6;
  for (int l=tid;l<LEN;l+=512) sm[l] = scores[(size_t)o*LEN + l];
  __syncthreads();
  float mx = -1e30f;
  for (int l=tid;l<LEN;l+=512) mx = fmaxf(mx, sm[l]);
  #pragma unroll
  for (int m=32;m;m>>=1) mx = fmaxf(mx, __shfl_xor(mx, m, 64));
  if (lane==0) red[wv] = mx;
  __syncthreads();
  if (tid==0){ float m0=red[0]; for (int i=1;i<8;i++) m0=fmaxf(m0,red[i]); bc[0]=m0; }
  __syncthreads();
  const float m0 = bc[0];
  float s = 0.f;
  for (int l=tid;l<LEN;l+=512){ float e = __expf(sm[l]-m0); sm[l]=e; s+=e; }
  #pragma unroll
  for (int m=32;m;m>>=1) s += __shfl_xor(s, m, 64);
  if (lane==0) red[wv] = s;
  __syncthreads();
  if (tid==0){ float z=0.f; for (int i=0;i<8;i++) z+=red[i]; bc[1] = 1.f/z; }
  __syncthreads();
  const float rz = bc[1];
  float acc = 0.f;
  const float* hp = hs + tid;
  for (int l=0;l<LEN;l++) acc += sm[l]*hp[(size_t)l*HID];
  ratt[(size_t)o*HID + tid] = acc*rz;
}

// ------- out[o] = sigmoid( dec_W[o] . tanh(r W_p^T + b_p + xw) + dec_b ) ----
__global__ __launch_bounds__(256) void final_kernel(
    const float* __restrict__ ratt, const float* __restrict__ Wp, const float* __restrict__ bp,
    const float* __restrict__ xw, const float* __restrict__ decW, const float* __restrict__ decb,
    float* __restrict__ outp)
{
  __shared__ float rv[HID];
  __shared__ float rr[HID];
  __shared__ float red[4];
  const int o = blockIdx.x, tid = threadIdx.x;
  const int lane = tid & 63, wv = tid >> 6;
  rv[tid]     = ratt[(size_t)o*HID + tid];
  rv[256+tid] = ratt[(size_t)o*HID + 256 + tid];
  __syncthreads();
  #pragma unroll
  for (int jj=0;jj<2;jj++){
    int j = tid + jj*256;
    const float* wr = Wp + (size_t)j*HID;
    float d = 0.f;
    for (int k=0;k<HID;k++) d += rv[k]*wr[k];
    rr[j] = tanh_(d + bp[j] + xw[j]);
  }
  __syncthreads();
  float v = rr[tid]*decW[(size_t)o*HID+tid] + rr[256+tid]*decW[(size_t)o*HID+256+tid];
  #pragma unroll
  for (int m=32;m;m>>=1) v += __shfl_xor(v, m, 64);
  if (lane==0) red[wv] = v;
  __syncthreads();
  if (tid==0) outp[o] = sigm_(red[0]+red[1]+red[2]+red[3] + decb[o]);
}

// ---------------------------------------------------------------------------
extern "C" void kernel_launch(void* const* d_in, const int* in_sizes, int n_in,
                              void* d_out, int out_size, void* d_ws, size_t ws_size,
                              hipStream_t stream)
{
  (void)in_sizes; (void)n_in; (void)out_size; (void)ws_size;
  const int*   sent  = (const int*)  d_in[0];
  const float* embed = (const float*)d_in[1];
  const float* WihF  = (const float*)d_in[2];
  const float* WhhF  = (const float*)d_in[3];
  const float* bihF  = (const float*)d_in[4];
  const float* bhhF  = (const float*)d_in[5];
  const float* WihB  = (const float*)d_in[6];
  const float* WhhB  = (const float*)d_in[7];
  const float* bihB  = (const float*)d_in[8];
  const float* bhhB  = (const float*)d_in[9];
  const float* AE    = (const float*)d_in[10];
  const float* W_h   = (const float*)d_in[11];
  const float* b_h   = (const float*)d_in[12];
  const float* W_v   = (const float*)d_in[13];
  const float* b_v   = (const float*)d_in[14];
  const float* w_a   = (const float*)d_in[15];
  const float* b_w   = (const float*)d_in[16];
  const float* W_p   = (const float*)d_in[17];
  const float* b_p   = (const float*)d_in[18];
  const float* W_x   = (const float*)d_in[19];
  const float* b_x   = (const float*)d_in[20];
  const float* decW  = (const float*)d_in[21];
  const float* decb  = (const float*)d_in[22];
  float* outp = (float*)d_out;

  char* ws = (char*)d_ws;
  size_t off = 0;
  auto alloc = [&](size_t n){ size_t p = off; off += (n + 255) & ~(size_t)255; return p; };
  __hip_bfloat16* preF  = (__hip_bfloat16*)(ws + alloc((size_t)LEN*G4*2));
  __hip_bfloat16* preB  = (__hip_bfloat16*)(ws + alloc((size_t)LEN*G4*2));
  float*          hsbuf = (float*)        (ws + alloc((size_t)LEN*HID*4));
  float*          WhOut = (float*)        (ws + alloc((size_t)LEN*HID*4));
  signed char*    Wq2   = (signed char*)  (ws + alloc((size_t)2*G4*HALF));
  float*          wsc4  = (float*)        (ws + alloc((size_t)2*HALF*4*4));
  float*          bsum  = (float*)        (ws + alloc((size_t)2*G4*4));
  float*          htv   = (float*)        (ws + alloc((size_t)HID*4));
  float*          WvAE  = (float*)        (ws + alloc((size_t)OUT_N*HID*4));
  float*          xw    = (float*)        (ws + alloc((size_t)HID*4));
  float*          scor  = (float*)        (ws + alloc((size_t)OUT_N*LEN*4));
  float*          ratt  = (float*)        (ws + alloc((size_t)OUT_N*HID*4));

  // prep
  prep_quant<<<8, 256, 0, stream>>>(WhhF, WhhB, bihF, bhhF, bihB, bhhB, Wq2, wsc4, bsum);
  wv_kernel<<<OUT_N, 256, 0, stream>>>(AE, W_v, b_v, WvAE);

  // pre = gather(embed, sent) @ Wih^T + (bih+bhh), bf16, gate-permuted cols
  gemm_tn<<<dim3(LEN/64, G4/64), 256, 0, stream>>>(
      embed, EMB, sent, WihF, EMB, bsum,        nullptr, preF, G4, LEN, G4, EMB, 1);
  gemm_tn<<<dim3(LEN/64, G4/64), 256, 0, stream>>>(
      embed, EMB, sent, WihB, EMB, bsum + G4,   nullptr, preB, G4, LEN, G4, EMB, 1);

  // sequential bidirectional scan (2 persistent blocks, MFMA inner product)
  lstm_scan<<<2, 512, 0, stream>>>(preF, preB, Wq2, wsc4, hsbuf, htv);

  // Wh_out = output2 @ W_h_a^T + b_h_a
  gemm_tn<<<dim3(LEN/64, HID/64), 256, 0, stream>>>(
      hsbuf, HID, nullptr, W_h, HID, b_h, WhOut, nullptr, HID, LEN, HID, HID, 0);

  xw_kernel<<<1, 512, 0, stream>>>(htv, W_x, b_x, xw);
  scores_kernel<<<LEN, 256, 0, stream>>>(WhOut, WvAE, w_a, b_w, scor);
  softmax_wsum<<<OUT_N, 512, 0, stream>>>(scor, hsbuf, ratt);
  final_kernel<<<OUT_N, 256, 0, stream>>>(ratt, W_p, b_p, xw, decW, decb, outp);
}